// Round 2
// baseline (1323.863 us; speedup 1.0000x reference)
//
#include <hip/hip_runtime.h>

typedef __bf16 bf16;
typedef __bf16 bf16x8 __attribute__((ext_vector_type(8)));
typedef float  f32x4  __attribute__((ext_vector_type(4)));

#define L_SEQ 1024
#define DM    1024
#define DI    2048
#define DTR   64
#define DSTATE 16
#define XD    96   // DTR + 2*DSTATE

__device__ __forceinline__ float bf2f(bf16 v){ return (float)v; }
__device__ __forceinline__ bf16  f2bf(float v){ return (bf16)v; }

// ---------------------------------------------------------------------------
// Generic MFMA GEMM, B^T layout: C[m][n] = sum_k A[m][k] * B[n][k]
// 128x128 tile, BK=64, 256 threads (4 waves, 2x2 of 64x64), 16x16x32 bf16 MFMA
// A is fp32 (AF32=true, raw input) or bf16 (intermediate); B is always fp32
// (weights); converted to bf16 during LDS staging. grid.z selects direction.
// ---------------------------------------------------------------------------
template<bool AF32>
__global__ __launch_bounds__(256) void gemm_bt(
    const void* __restrict__ Av, const float* __restrict__ B0, const float* __restrict__ B1,
    void* __restrict__ Cv,
    int M, int N, int K, int lda, int ldb, int ldc,
    long aOffZ, long cOffZ,
    const float* __restrict__ bias0, const float* __restrict__ bias1,
    int flipA1, int writeBf16, int act)
{
  const int tid  = threadIdx.x;
  const int z    = blockIdx.z;
  const float* Bp   = z ? B1 : B0;
  const float* bias = z ? bias1 : bias0;
  const int flip = z ? flipA1 : 0;
  const int bm = blockIdx.x * 128;
  const int bn = blockIdx.y * 128;

  __shared__ bf16 As[128][72];   // +8 pad: frag ds_read_b128 -> 2-way (free)
  __shared__ bf16 Bs[128][72];

  f32x4 acc[4][4];
  f32x4 z4; z4[0]=0.f; z4[1]=0.f; z4[2]=0.f; z4[3]=0.f;
  #pragma unroll
  for (int i=0;i<4;i++)
    #pragma unroll
    for (int j=0;j<4;j++) acc[i][j] = z4;

  const int wave = tid >> 6;
  const int lane = tid & 63;
  const int wm = (wave >> 1) * 64;
  const int wn = (wave & 1) * 64;
  const int fr = lane & 15;          // fragment row (m for A, n for B)
  const int kq = (lane >> 4) * 8;    // k-offset of this quad

  const int srow = tid >> 1;         // staging row 0..127
  const int scol = (tid & 1) * 32;   // staging col half

  int ar  = bm + srow;
  int agr = flip ? (M - 1 - ar) : ar;
  const float* aF = (const float*)Av + (long)z * aOffZ + (long)agr * lda + scol;
  const bf16*  aH = (const bf16*) Av + (long)z * aOffZ + (long)agr * lda + scol;
  int br = bn + srow;
  const float* bBase = Bp + (long)br * ldb + scol;
  const bool bOk = (br < N);

  for (int k0 = 0; k0 < K; k0 += 64) {
    // stage A tile (convert fp32->bf16 if needed)
    if (AF32) {
      #pragma unroll
      for (int j = 0; j < 4; j++) {
        f32x4 v0 = *(const f32x4*)(aF + k0 + j*8);
        f32x4 v1 = *(const f32x4*)(aF + k0 + j*8 + 4);
        bf16x8 t;
        #pragma unroll
        for (int q = 0; q < 4; q++) { t[q] = (bf16)v0[q]; t[4+q] = (bf16)v1[q]; }
        *(bf16x8*)&As[srow][scol + j*8] = t;
      }
    } else {
      #pragma unroll
      for (int j = 0; j < 4; j++)
        *(bf16x8*)&As[srow][scol + j*8] = *(const bf16x8*)(aH + k0 + j*8);
    }
    // stage B tile (fp32 weights -> bf16)
    #pragma unroll
    for (int j = 0; j < 4; j++) {
      bf16x8 t;
      if (bOk) {
        f32x4 v0 = *(const f32x4*)(bBase + k0 + j*8);
        f32x4 v1 = *(const f32x4*)(bBase + k0 + j*8 + 4);
        #pragma unroll
        for (int q = 0; q < 4; q++) { t[q] = (bf16)v0[q]; t[4+q] = (bf16)v1[q]; }
      } else {
        #pragma unroll
        for (int q = 0; q < 8; q++) t[q] = (bf16)0.f;
      }
      *(bf16x8*)&Bs[srow][scol + j*8] = t;
    }
    __syncthreads();

    #pragma unroll
    for (int ks = 0; ks < 64; ks += 32) {
      bf16x8 af[4], bfr[4];
      #pragma unroll
      for (int i=0;i<4;i++) af[i]  = *(const bf16x8*)&As[wm + i*16 + fr][ks + kq];
      #pragma unroll
      for (int j=0;j<4;j++) bfr[j] = *(const bf16x8*)&Bs[wn + j*16 + fr][ks + kq];
      #pragma unroll
      for (int i=0;i<4;i++)
        #pragma unroll
        for (int j=0;j<4;j++)
          acc[i][j] = __builtin_amdgcn_mfma_f32_16x16x32_bf16(af[i], bfr[j], acc[i][j], 0, 0, 0);
    }
    __syncthreads();
  }

  // epilogue: C/D layout col=lane&15, row=(lane>>4)*4+reg
  const int rr = (lane >> 4) * 4;
  const int cc = lane & 15;
  #pragma unroll
  for (int i=0;i<4;i++) {
    #pragma unroll
    for (int j=0;j<4;j++) {
      int gn = bn + wn + j*16 + cc;
      if (gn >= N) continue;
      float bv = bias ? bias[gn] : 0.f;
      #pragma unroll
      for (int r=0;r<4;r++) {
        int gm = bm + wm + i*16 + rr + r;
        float v = acc[i][j][r] + bv;
        if (act == 1) v = (v > 20.f) ? v : log1pf(__expf(v));  // softplus
        long idx = (long)z * cOffZ + (long)gm * ldc + gn;
        if (writeBf16) ((bf16*)Cv)[idx] = f2bf(v);
        else           ((float*)Cv)[idx] = v;
      }
    }
  }
}

// ---------------------------------------------------------------------------
// depthwise causal conv(4) + bias + silu : u[dir][l][d]
// ---------------------------------------------------------------------------
__global__ __launch_bounds__(256) void conv_silu_k(
    const bf16* __restrict__ xz, const float* __restrict__ cw0, const float* __restrict__ cw1,
    const float* __restrict__ cb0, const float* __restrict__ cb1, bf16* __restrict__ u)
{
  int gid = blockIdx.x * 256 + threadIdx.x;       // over 2 * L * DI = 2^22
  int dir = gid >> 21;
  int rem = gid & ((1 << 21) - 1);
  int l = rem >> 11;
  int d = rem & (DI - 1);
  const float* w   = dir ? cw1 : cw0;
  const float* b   = dir ? cb1 : cb0;
  const bf16* xzd = xz + (long)dir * L_SEQ * (2 * DI);
  float acc = b[d];
  #pragma unroll
  for (int j = 0; j < 4; j++) {
    int ll = l - 3 + j;
    if (ll >= 0) acc += w[d * 4 + j] * bf2f(xzd[(long)ll * (2 * DI) + d]);
  }
  float s = acc / (1.f + __expf(-acc));
  u[(long)dir * L_SEQ * DI + (long)l * DI + d] = f2bf(s);
}

// ---------------------------------------------------------------------------
// selective scan: one thread per channel, h[16] in regs, B/C chunk-staged in LDS
// delta lives in the (dead) xi columns of xz; z in the z columns; g written
// in-place over u (same (l,d) read-then-write by the same thread => safe).
// ---------------------------------------------------------------------------
__global__ __launch_bounds__(256) void scan_k(
    const bf16* xz, const bf16* u, const bf16* xdbl,
    const float* __restrict__ Alog0, const float* __restrict__ Alog1,
    const float* __restrict__ Dp0, const float* __restrict__ Dp1,
    bf16* g)
{
  const int tid = threadIdx.x;
  const int dir = blockIdx.y;
  const int d = blockIdx.x * 256 + tid;
  const float* Alog = dir ? Alog1 : Alog0;
  const float* Dp   = dir ? Dp1 : Dp0;
  const bf16* row0 = xz + (long)dir * L_SEQ * (2 * DI);   // delta @ +d, z @ +DI+d
  const bf16* ud   = u  + (long)dir * L_SEQ * DI;
  const bf16* xd   = xdbl + (long)dir * L_SEQ * XD;
  bf16* gd = g + (long)dir * L_SEQ * DI;

  float An[16], h[16];
  #pragma unroll
  for (int n = 0; n < 16; n++) {
    An[n] = -__expf(Alog[d * 16 + n]);
    h[n] = 0.f;
  }
  const float Dpv = Dp[d];

  __shared__ float lb[128][16];
  __shared__ float lcs[128][16];

  for (int lc0 = 0; lc0 < L_SEQ; lc0 += 128) {
    __syncthreads();
    {
      int ll = tid >> 1, sel = tid & 1;
      const bf16* p = xd + (long)(lc0 + ll) * XD + DTR + sel * 16;
      bf16x8 v0 = *(const bf16x8*)p;
      bf16x8 v1 = *(const bf16x8*)(p + 8);
      float* dst = sel ? &lcs[ll][0] : &lb[ll][0];
      #pragma unroll
      for (int j = 0; j < 8; j++) { dst[j] = bf2f(v0[j]); dst[8 + j] = bf2f(v1[j]); }
    }
    __syncthreads();
    for (int ll = 0; ll < 128; ll++) {
      int l = lc0 + ll;
      float dlt = bf2f(row0[(long)l * (2 * DI) + d]);
      float zv  = bf2f(row0[(long)l * (2 * DI) + DI + d]);
      float uu  = bf2f(ud[(long)l * DI + d]);
      float du = dlt * uu;
      float y = 0.f;
      #pragma unroll
      for (int n = 0; n < 16; n++) {
        float a = __expf(dlt * An[n]);
        h[n] = h[n] * a + du * lb[ll][n];
        y += h[n] * lcs[ll][n];
      }
      y += uu * Dpv;
      float sz = zv / (1.f + __expf(-zv));
      gd[(long)l * DI + d] = f2bf(y * sz);
    }
  }
}

// ---------------------------------------------------------------------------
// fused = [oproj_fw + x , flip(oproj_bw) + x]  (bf16, 1024 x 2048)
// ---------------------------------------------------------------------------
__global__ __launch_bounds__(256) void fuse_k(
    const float* __restrict__ oproj, const float* __restrict__ x, bf16* __restrict__ fused)
{
  int gid = blockIdx.x * 256 + threadIdx.x;  // over L * 2*DM = 2^21
  int l = gid >> 11;
  int c = gid & (2 * DM - 1);
  float v;
  if (c < DM) {
    v = oproj[(long)l * DM + c] + x[(long)l * DM + c];
  } else {
    int cc = c - DM;
    v = oproj[(long)L_SEQ * DM + (long)(L_SEQ - 1 - l) * DM + cc] + x[(long)l * DM + cc];
  }
  fused[gid] = f2bf(v);
}

// ---------------------------------------------------------------------------
// +proj_b then LayerNorm over last dim (1024), write fp32 out
// ---------------------------------------------------------------------------
__global__ __launch_bounds__(256) void ln_k(
    const float* __restrict__ fin, const float* __restrict__ pb,
    const float* __restrict__ lnw, const float* __restrict__ lnb, float* __restrict__ out)
{
  int row = blockIdx.x;
  int tid = threadIdx.x;
  float v[4]; float s1 = 0.f, s2 = 0.f;
  #pragma unroll
  for (int j = 0; j < 4; j++) {
    int c = tid + j * 256;
    v[j] = fin[(long)row * DM + c] + pb[c];
    s1 += v[j]; s2 += v[j] * v[j];
  }
  #pragma unroll
  for (int off = 32; off; off >>= 1) { s1 += __shfl_down(s1, off); s2 += __shfl_down(s2, off); }
  __shared__ float red[8];
  int wave = tid >> 6, lane = tid & 63;
  if (lane == 0) { red[wave] = s1; red[4 + wave] = s2; }
  __syncthreads();
  float t1 = red[0] + red[1] + red[2] + red[3];
  float t2 = red[4] + red[5] + red[6] + red[7];
  float mu = t1 / DM;
  float var = t2 / DM - mu * mu;
  float inv = rsqrtf(var + 1e-5f);
  #pragma unroll
  for (int j = 0; j < 4; j++) {
    int c = tid + j * 256;
    out[(long)row * DM + c] = (v[j] - mu) * inv * lnw[c] + lnb[c];
  }
}

// ---------------------------------------------------------------------------
extern "C" void kernel_launch(void* const* d_in, const int* in_sizes, int n_in,
                              void* d_out, int out_size, void* d_ws, size_t ws_size,
                              hipStream_t stream)
{
  const float* x         = (const float*)d_in[0];
  const float* fw_in_w   = (const float*)d_in[1];
  const float* fw_conv_w = (const float*)d_in[2];
  const float* fw_conv_b = (const float*)d_in[3];
  const float* fw_xproj_w= (const float*)d_in[4];
  const float* fw_dt_w   = (const float*)d_in[5];
  const float* fw_dt_b   = (const float*)d_in[6];
  const float* fw_Alog   = (const float*)d_in[7];
  const float* fw_Dp     = (const float*)d_in[8];
  const float* fw_out_w  = (const float*)d_in[9];
  const float* bw_in_w   = (const float*)d_in[10];
  const float* bw_conv_w = (const float*)d_in[11];
  const float* bw_conv_b = (const float*)d_in[12];
  const float* bw_xproj_w= (const float*)d_in[13];
  const float* bw_dt_w   = (const float*)d_in[14];
  const float* bw_dt_b   = (const float*)d_in[15];
  const float* bw_Alog   = (const float*)d_in[16];
  const float* bw_Dp     = (const float*)d_in[17];
  const float* bw_out_w  = (const float*)d_in[18];
  const float* proj_w    = (const float*)d_in[19];
  const float* proj_b    = (const float*)d_in[20];
  const float* ln_w      = (const float*)d_in[21];
  const float* ln_b      = (const float*)d_in[22];

  // workspace layout (peak 24.4 MB):
  //   phase 1 (through scan):  xz bf16 [2][1024][4096] @ 0..16MB
  //                            u/g bf16 [2][1024][2048] @ 16..24MB
  //                            xdbl bf16 [2][1024][96]  @ 24..24.4MB
  //     (delta is written into the dead xi-columns of xz; g in-place over u)
  //   phase 2 (after scan):    oproj f32 [2][1024][1024] @ 0..8MB (xz dead)
  //                            fused bf16 [1024][2048]   @ 8..12MB
  //                            fin  f32  [1024][1024]    @ 12..16MB
  char* ws = (char*)d_ws;
  const size_t MB = 1024 * 1024;
  bf16*  xz    = (bf16*)(ws + 0);
  bf16*  u     = (bf16*)(ws + 16 * MB);
  bf16*  xdbl  = (bf16*)(ws + 24 * MB);
  bf16*  g     = u;                       // in-place
  bf16*  delta = xz;                      // xi columns, stride 4096
  float* oproj = (float*)(ws + 0);
  bf16*  fused = (bf16*)(ws + 8 * MB);
  float* fin   = (float*)(ws + 12 * MB);

  dim3 blk(256);

  // 1. in-proj: xz[dir] = (flip?)x @ in_w^T   (M=1024, N=4096, K=1024)
  gemm_bt<true><<<dim3(8, 32, 2), blk, 0, stream>>>(
      x, fw_in_w, bw_in_w, (void*)xz, 1024, 4096, 1024, 1024, 1024, 4096,
      0L, (long)1024 * 4096, nullptr, nullptr, 1, 1, 0);

  // 2. depthwise conv + silu -> u
  conv_silu_k<<<16384, blk, 0, stream>>>(xz, fw_conv_w, bw_conv_w, fw_conv_b, bw_conv_b, u);

  // 3. x_dbl = u @ xproj_w^T   (N=96)
  gemm_bt<false><<<dim3(8, 1, 2), blk, 0, stream>>>(
      u, fw_xproj_w, bw_xproj_w, (void*)xdbl, 1024, 96, 2048, 2048, 2048, 96,
      (long)1024 * 2048, (long)1024 * 96, nullptr, nullptr, 0, 1, 0);

  // 4. delta = softplus(dt @ dt_w^T + dt_b) -> stored into xi cols of xz (ldc=4096)
  gemm_bt<false><<<dim3(8, 16, 2), blk, 0, stream>>>(
      xdbl, fw_dt_w, bw_dt_w, (void*)delta, 1024, 2048, 64, 96, 64, 4096,
      (long)1024 * 96, (long)1024 * 4096, fw_dt_b, bw_dt_b, 0, 1, 1);

  // 5. selective scan -> g = (y + u*Dp)*silu(z)   (in-place over u)
  scan_k<<<dim3(8, 2), blk, 0, stream>>>(xz, u, xdbl, fw_Alog, bw_Alog, fw_Dp, bw_Dp, g);

  // 6. out-proj: oproj[dir] = g @ out_w^T (fp32 out)
  gemm_bt<false><<<dim3(8, 8, 2), blk, 0, stream>>>(
      g, fw_out_w, bw_out_w, (void*)oproj, 1024, 1024, 2048, 2048, 2048, 1024,
      (long)1024 * 2048, (long)1024 * 1024, nullptr, nullptr, 0, 0, 0);

  // 7. residual + unflip + concat -> fused (bf16 1024x2048)
  fuse_k<<<8192, blk, 0, stream>>>(oproj, x, fused);

  // 8. final proj: fin = fused @ proj_w^T (fp32 out)
  gemm_bt<false><<<dim3(8, 8, 1), blk, 0, stream>>>(
      fused, proj_w, proj_w, (void*)fin, 1024, 1024, 2048, 2048, 2048, 1024,
      0L, 0L, nullptr, nullptr, 0, 0, 0);

  // 9. +proj_b, LayerNorm -> d_out (fp32)
  ln_k<<<1024, blk, 0, stream>>>(fin, proj_b, ln_w, ln_b, (float*)d_out);
}

// Round 3
// 571.273 us; speedup vs baseline: 2.3174x; 2.3174x over previous
//
#include <hip/hip_runtime.h>

typedef __bf16 bf16;
typedef __bf16 bf16x8 __attribute__((ext_vector_type(8)));
typedef float  f32x4  __attribute__((ext_vector_type(4)));

#define L_SEQ 1024
#define DM    1024
#define DI    2048
#define DTR   64
#define DSTATE 16
#define XD    96   // DTR + 2*DSTATE
#define NC    32   // scan chunks
#define CS    32   // steps per chunk (L_SEQ / NC)

__device__ __forceinline__ float bf2f(bf16 v){ return (float)v; }
__device__ __forceinline__ bf16  f2bf(float v){ return (bf16)v; }

// ---------------------------------------------------------------------------
// Generic MFMA GEMM, B^T layout: C[m][n] = sum_k A[m][k] * B[n][k]
// 128x128 tile, BK=64, 256 threads (4 waves, 2x2 of 64x64), 16x16x32 bf16 MFMA
// ---------------------------------------------------------------------------
template<bool AF32>
__global__ __launch_bounds__(256) void gemm_bt(
    const void* __restrict__ Av, const float* __restrict__ B0, const float* __restrict__ B1,
    void* __restrict__ Cv,
    int M, int N, int K, int lda, int ldb, int ldc,
    long aOffZ, long cOffZ,
    const float* __restrict__ bias0, const float* __restrict__ bias1,
    int flipA1, int writeBf16, int act)
{
  const int tid  = threadIdx.x;
  const int z    = blockIdx.z;
  const float* Bp   = z ? B1 : B0;
  const float* bias = z ? bias1 : bias0;
  const int flip = z ? flipA1 : 0;
  const int bm = blockIdx.x * 128;
  const int bn = blockIdx.y * 128;

  __shared__ bf16 As[128][72];   // +8 pad: frag ds_read_b128 -> 2-way (free)
  __shared__ bf16 Bs[128][72];

  f32x4 acc[4][4];
  f32x4 z4; z4[0]=0.f; z4[1]=0.f; z4[2]=0.f; z4[3]=0.f;
  #pragma unroll
  for (int i=0;i<4;i++)
    #pragma unroll
    for (int j=0;j<4;j++) acc[i][j] = z4;

  const int wave = tid >> 6;
  const int lane = tid & 63;
  const int wm = (wave >> 1) * 64;
  const int wn = (wave & 1) * 64;
  const int fr = lane & 15;
  const int kq = (lane >> 4) * 8;

  const int srow = tid >> 1;
  const int scol = (tid & 1) * 32;

  int ar  = bm + srow;
  int agr = flip ? (M - 1 - ar) : ar;
  const float* aF = (const float*)Av + (long)z * aOffZ + (long)agr * lda + scol;
  const bf16*  aH = (const bf16*) Av + (long)z * aOffZ + (long)agr * lda + scol;
  int br = bn + srow;
  const float* bBase = Bp + (long)br * ldb + scol;
  const bool bOk = (br < N);

  for (int k0 = 0; k0 < K; k0 += 64) {
    if (AF32) {
      #pragma unroll
      for (int j = 0; j < 4; j++) {
        f32x4 v0 = *(const f32x4*)(aF + k0 + j*8);
        f32x4 v1 = *(const f32x4*)(aF + k0 + j*8 + 4);
        bf16x8 t;
        #pragma unroll
        for (int q = 0; q < 4; q++) { t[q] = (bf16)v0[q]; t[4+q] = (bf16)v1[q]; }
        *(bf16x8*)&As[srow][scol + j*8] = t;
      }
    } else {
      #pragma unroll
      for (int j = 0; j < 4; j++)
        *(bf16x8*)&As[srow][scol + j*8] = *(const bf16x8*)(aH + k0 + j*8);
    }
    #pragma unroll
    for (int j = 0; j < 4; j++) {
      bf16x8 t;
      if (bOk) {
        f32x4 v0 = *(const f32x4*)(bBase + k0 + j*8);
        f32x4 v1 = *(const f32x4*)(bBase + k0 + j*8 + 4);
        #pragma unroll
        for (int q = 0; q < 4; q++) { t[q] = (bf16)v0[q]; t[4+q] = (bf16)v1[q]; }
      } else {
        #pragma unroll
        for (int q = 0; q < 8; q++) t[q] = (bf16)0.f;
      }
      *(bf16x8*)&Bs[srow][scol + j*8] = t;
    }
    __syncthreads();

    #pragma unroll
    for (int ks = 0; ks < 64; ks += 32) {
      bf16x8 af[4], bfr[4];
      #pragma unroll
      for (int i=0;i<4;i++) af[i]  = *(const bf16x8*)&As[wm + i*16 + fr][ks + kq];
      #pragma unroll
      for (int j=0;j<4;j++) bfr[j] = *(const bf16x8*)&Bs[wn + j*16 + fr][ks + kq];
      #pragma unroll
      for (int i=0;i<4;i++)
        #pragma unroll
        for (int j=0;j<4;j++)
          acc[i][j] = __builtin_amdgcn_mfma_f32_16x16x32_bf16(af[i], bfr[j], acc[i][j], 0, 0, 0);
    }
    __syncthreads();
  }

  const int rr = (lane >> 4) * 4;
  const int cc = lane & 15;
  #pragma unroll
  for (int i=0;i<4;i++) {
    #pragma unroll
    for (int j=0;j<4;j++) {
      int gn = bn + wn + j*16 + cc;
      if (gn >= N) continue;
      float bv = bias ? bias[gn] : 0.f;
      #pragma unroll
      for (int r=0;r<4;r++) {
        int gm = bm + wm + i*16 + rr + r;
        float v = acc[i][j][r] + bv;
        if (act == 1) v = (v > 20.f) ? v : log1pf(__expf(v));  // softplus
        long idx = (long)z * cOffZ + (long)gm * ldc + gn;
        if (writeBf16) ((bf16*)Cv)[idx] = f2bf(v);
        else           ((float*)Cv)[idx] = v;
      }
    }
  }
}

// ---------------------------------------------------------------------------
// depthwise causal conv(4) + bias + silu : u[dir][l][d]
// ---------------------------------------------------------------------------
__global__ __launch_bounds__(256) void conv_silu_k(
    const bf16* __restrict__ xz, const float* __restrict__ cw0, const float* __restrict__ cw1,
    const float* __restrict__ cb0, const float* __restrict__ cb1, bf16* __restrict__ u)
{
  int gid = blockIdx.x * 256 + threadIdx.x;       // over 2 * L * DI = 2^22
  int dir = gid >> 21;
  int rem = gid & ((1 << 21) - 1);
  int l = rem >> 11;
  int d = rem & (DI - 1);
  const float* w   = dir ? cw1 : cw0;
  const float* b   = dir ? cb1 : cb0;
  const bf16* xzd = xz + (long)dir * L_SEQ * (2 * DI);
  float acc = b[d];
  #pragma unroll
  for (int j = 0; j < 4; j++) {
    int ll = l - 3 + j;
    if (ll >= 0) acc += w[d * 4 + j] * bf2f(xzd[(long)ll * (2 * DI) + d]);
  }
  float s = acc / (1.f + __expf(-acc));
  u[(long)dir * L_SEQ * DI + (long)l * DI + d] = f2bf(s);
}

// ---------------------------------------------------------------------------
// Chunk-parallel selective scan.
//   a[l][n] = exp(delta[l]*An[n])  =>  prod over chunk = exp(An * sum(delta))
// p1: per (dir,chunk,d): local scan from h=0 -> hout[dir][c][d][16] (bf16),
//     sumd[dir][c][d] (f32)
// p2: per (dir,d,n): 32-step serial combine; hout[c] overwritten with h_start
// p3: per (dir,chunk,d): rescan from h_start, emit g = (y+u*Dp)*silu(z)
// ---------------------------------------------------------------------------
__global__ __launch_bounds__(256) void scan_p1(
    const bf16* __restrict__ xz, const bf16* __restrict__ u, const bf16* __restrict__ xdbl,
    const float* __restrict__ Alog0, const float* __restrict__ Alog1,
    bf16* __restrict__ hout, float* __restrict__ sumd)
{
  const int tid = threadIdx.x;
  const int c   = blockIdx.y;
  const int dir = blockIdx.z;
  const int d   = blockIdx.x * 256 + tid;
  const float* Alog = dir ? Alog1 : Alog0;
  const bf16* dl = xz + (long)dir * L_SEQ * (2 * DI);       // delta in xi cols
  const bf16* ud = u  + (long)dir * L_SEQ * DI;
  const bf16* xd = xdbl + (long)dir * L_SEQ * XD;
  const int l0 = c * CS;

  __shared__ float lb[CS][16];
  {
    int i = tid * 2;                  // CS*16 = 512 elements, 2/thread
    int ll = i >> 4, n = i & 15;      // n even
    const bf16* p = xd + (long)(l0 + ll) * XD + DTR + n;
    lb[ll][n]     = bf2f(p[0]);
    lb[ll][n + 1] = bf2f(p[1]);
  }
  __syncthreads();

  float An[16], h[16];
  #pragma unroll
  for (int n = 0; n < 16; n++) { An[n] = -__expf(Alog[d * 16 + n]); h[n] = 0.f; }
  float sd = 0.f;

  #pragma unroll 4
  for (int ll = 0; ll < CS; ll++) {
    int l = l0 + ll;
    float dlt = bf2f(dl[(long)l * (2 * DI) + d]);
    float uu  = bf2f(ud[(long)l * DI + d]);
    sd += dlt;
    float du = dlt * uu;
    #pragma unroll
    for (int n = 0; n < 16; n++) {
      float a = __expf(dlt * An[n]);
      h[n] = h[n] * a + du * lb[ll][n];
    }
  }

  bf16* hp = hout + (((long)dir * NC + c) * DI + d) * 16;
  bf16x8 o0, o1;
  #pragma unroll
  for (int n = 0; n < 8; n++) { o0[n] = f2bf(h[n]); o1[n] = f2bf(h[8 + n]); }
  *(bf16x8*)hp = o0;
  *(bf16x8*)(hp + 8) = o1;
  sumd[((long)dir * NC + c) * DI + d] = sd;
}

__global__ __launch_bounds__(256) void scan_p2(
    const float* __restrict__ Alog0, const float* __restrict__ Alog1,
    bf16* hout, const float* __restrict__ sumd)
{
  int g = blockIdx.x * 256 + threadIdx.x;   // 2*2048*16 = 65536
  int dir = g >> 15;
  int rem = g & 32767;
  int d = rem >> 4;
  int n = rem & 15;
  const float* Alog = dir ? Alog1 : Alog0;
  float An = -__expf(Alog[d * 16 + n]);
  float hs = 0.f;
  for (int c = 0; c < NC; c++) {
    long base = ((long)dir * NC + c) * DI + d;
    float tmp = bf2f(hout[base * 16 + n]);
    float P = __expf(An * sumd[base]);
    hout[base * 16 + n] = f2bf(hs);   // h_start for chunk c
    hs = P * hs + tmp;
  }
}

__global__ __launch_bounds__(256) void scan_p3(
    const bf16* xz, const bf16* u, const bf16* __restrict__ xdbl,
    const float* __restrict__ Alog0, const float* __restrict__ Alog1,
    const float* __restrict__ Dp0, const float* __restrict__ Dp1,
    const bf16* __restrict__ hout, bf16* g)
{
  const int tid = threadIdx.x;
  const int c   = blockIdx.y;
  const int dir = blockIdx.z;
  const int d   = blockIdx.x * 256 + tid;
  const float* Alog = dir ? Alog1 : Alog0;
  const float* Dp   = dir ? Dp1 : Dp0;
  const bf16* row0 = xz + (long)dir * L_SEQ * (2 * DI);   // delta @ +d, z @ +DI+d
  const bf16* ud   = u  + (long)dir * L_SEQ * DI;
  const bf16* xd   = xdbl + (long)dir * L_SEQ * XD;
  bf16* gd = g + (long)dir * L_SEQ * DI;
  const int l0 = c * CS;

  __shared__ float lb[CS][16];
  __shared__ float lc[CS][16];
  {
    int i = tid * 4;                  // CS*32 = 1024 elements, 4/thread
    int ll = i >> 5, j = i & 31;      // j multiple of 4
    const bf16* p = xd + (long)(l0 + ll) * XD + DTR + j;
    #pragma unroll
    for (int q = 0; q < 4; q++) {
      int jj = j + q;
      float v = bf2f(p[q]);
      if (jj < 16) lb[ll][jj] = v; else lc[ll][jj - 16] = v;
    }
  }
  __syncthreads();

  float An[16], h[16];
  const bf16* hp = hout + (((long)dir * NC + c) * DI + d) * 16;
  #pragma unroll
  for (int n = 0; n < 16; n++) {
    An[n] = -__expf(Alog[d * 16 + n]);
    h[n] = bf2f(hp[n]);
  }
  const float Dpv = Dp[d];

  #pragma unroll 4
  for (int ll = 0; ll < CS; ll++) {
    int l = l0 + ll;
    float dlt = bf2f(row0[(long)l * (2 * DI) + d]);
    float zv  = bf2f(row0[(long)l * (2 * DI) + DI + d]);
    float uu  = bf2f(ud[(long)l * DI + d]);
    float du = dlt * uu;
    float y = 0.f;
    #pragma unroll
    for (int n = 0; n < 16; n++) {
      float a = __expf(dlt * An[n]);
      h[n] = h[n] * a + du * lb[ll][n];
      y += h[n] * lc[ll][n];
    }
    y += uu * Dpv;
    float sz = zv / (1.f + __expf(-zv));
    gd[(long)l * DI + d] = f2bf(y * sz);
  }
}

// ---------------------------------------------------------------------------
// fused = [oproj_fw + x , flip(oproj_bw) + x]  (bf16, 1024 x 2048)
// ---------------------------------------------------------------------------
__global__ __launch_bounds__(256) void fuse_k(
    const float* __restrict__ oproj, const float* __restrict__ x, bf16* __restrict__ fused)
{
  int gid = blockIdx.x * 256 + threadIdx.x;  // over L * 2*DM = 2^21
  int l = gid >> 11;
  int c = gid & (2 * DM - 1);
  float v;
  if (c < DM) {
    v = oproj[(long)l * DM + c] + x[(long)l * DM + c];
  } else {
    int cc = c - DM;
    v = oproj[(long)L_SEQ * DM + (long)(L_SEQ - 1 - l) * DM + cc] + x[(long)l * DM + cc];
  }
  fused[gid] = f2bf(v);
}

// ---------------------------------------------------------------------------
// +proj_b then LayerNorm over last dim (1024), write fp32 out
// ---------------------------------------------------------------------------
__global__ __launch_bounds__(256) void ln_k(
    const float* __restrict__ fin, const float* __restrict__ pb,
    const float* __restrict__ lnw, const float* __restrict__ lnb, float* __restrict__ out)
{
  int row = blockIdx.x;
  int tid = threadIdx.x;
  float v[4]; float s1 = 0.f, s2 = 0.f;
  #pragma unroll
  for (int j = 0; j < 4; j++) {
    int c = tid + j * 256;
    v[j] = fin[(long)row * DM + c] + pb[c];
    s1 += v[j]; s2 += v[j] * v[j];
  }
  #pragma unroll
  for (int off = 32; off; off >>= 1) { s1 += __shfl_down(s1, off); s2 += __shfl_down(s2, off); }
  __shared__ float red[8];
  int wave = tid >> 6, lane = tid & 63;
  if (lane == 0) { red[wave] = s1; red[4 + wave] = s2; }
  __syncthreads();
  float t1 = red[0] + red[1] + red[2] + red[3];
  float t2 = red[4] + red[5] + red[6] + red[7];
  float mu = t1 / DM;
  float var = t2 / DM - mu * mu;
  float inv = rsqrtf(var + 1e-5f);
  #pragma unroll
  for (int j = 0; j < 4; j++) {
    int c = tid + j * 256;
    out[(long)row * DM + c] = (v[j] - mu) * inv * lnw[c] + lnb[c];
  }
}

// ---------------------------------------------------------------------------
extern "C" void kernel_launch(void* const* d_in, const int* in_sizes, int n_in,
                              void* d_out, int out_size, void* d_ws, size_t ws_size,
                              hipStream_t stream)
{
  const float* x         = (const float*)d_in[0];
  const float* fw_in_w   = (const float*)d_in[1];
  const float* fw_conv_w = (const float*)d_in[2];
  const float* fw_conv_b = (const float*)d_in[3];
  const float* fw_xproj_w= (const float*)d_in[4];
  const float* fw_dt_w   = (const float*)d_in[5];
  const float* fw_dt_b   = (const float*)d_in[6];
  const float* fw_Alog   = (const float*)d_in[7];
  const float* fw_Dp     = (const float*)d_in[8];
  const float* fw_out_w  = (const float*)d_in[9];
  const float* bw_in_w   = (const float*)d_in[10];
  const float* bw_conv_w = (const float*)d_in[11];
  const float* bw_conv_b = (const float*)d_in[12];
  const float* bw_xproj_w= (const float*)d_in[13];
  const float* bw_dt_w   = (const float*)d_in[14];
  const float* bw_dt_b   = (const float*)d_in[15];
  const float* bw_Alog   = (const float*)d_in[16];
  const float* bw_Dp     = (const float*)d_in[17];
  const float* bw_out_w  = (const float*)d_in[18];
  const float* proj_w    = (const float*)d_in[19];
  const float* proj_b    = (const float*)d_in[20];
  const float* ln_w      = (const float*)d_in[21];
  const float* ln_b      = (const float*)d_in[22];

  // workspace layout (peak 30 MB):
  //   xz bf16 [2][1024][4096]  @ 0..16MB     (delta overwrites xi cols)
  //   u/g bf16 [2][1024][2048] @ 16..24MB    (g in-place over u)
  //   xdbl bf16 [2][1024][96]  @ 24..24.4MB
  //   sumd f32 [2][32][2048]   @ 25..25.5MB
  //   hout bf16 [2][32][2048][16] @ 26..30MB
  //   phase 2: oproj f32 @0..8, fused bf16 @8..12, fin f32 @12..16 (xz dead)
  char* ws = (char*)d_ws;
  const size_t MB = 1024 * 1024;
  bf16*  xz    = (bf16*)(ws + 0);
  bf16*  u     = (bf16*)(ws + 16 * MB);
  bf16*  xdbl  = (bf16*)(ws + 24 * MB);
  float* sumd  = (float*)(ws + 25 * MB);
  bf16*  hout  = (bf16*)(ws + 26 * MB);
  bf16*  g     = u;                       // in-place
  bf16*  delta = xz;                      // xi columns, stride 4096
  float* oproj = (float*)(ws + 0);
  bf16*  fused = (bf16*)(ws + 8 * MB);
  float* fin   = (float*)(ws + 12 * MB);

  dim3 blk(256);

  // 1. in-proj: xz[dir] = (flip?)x @ in_w^T   (M=1024, N=4096, K=1024)
  gemm_bt<true><<<dim3(8, 32, 2), blk, 0, stream>>>(
      x, fw_in_w, bw_in_w, (void*)xz, 1024, 4096, 1024, 1024, 1024, 4096,
      0L, (long)1024 * 4096, nullptr, nullptr, 1, 1, 0);

  // 2. depthwise conv + silu -> u
  conv_silu_k<<<16384, blk, 0, stream>>>(xz, fw_conv_w, bw_conv_w, fw_conv_b, bw_conv_b, u);

  // 3. x_dbl = u @ xproj_w^T   (N=96)
  gemm_bt<false><<<dim3(8, 1, 2), blk, 0, stream>>>(
      u, fw_xproj_w, bw_xproj_w, (void*)xdbl, 1024, 96, 2048, 2048, 2048, 96,
      (long)1024 * 2048, (long)1024 * 96, nullptr, nullptr, 0, 1, 0);

  // 4. delta = softplus(dt @ dt_w^T + dt_b) -> stored into xi cols of xz (ldc=4096)
  gemm_bt<false><<<dim3(8, 16, 2), blk, 0, stream>>>(
      xdbl, fw_dt_w, bw_dt_w, (void*)delta, 1024, 2048, 64, 96, 64, 4096,
      (long)1024 * 96, (long)1024 * 4096, fw_dt_b, bw_dt_b, 0, 1, 1);

  // 5. chunk-parallel selective scan -> g = (y + u*Dp)*silu(z)  (in-place over u)
  scan_p1<<<dim3(8, NC, 2), blk, 0, stream>>>(xz, u, xdbl, fw_Alog, bw_Alog, hout, sumd);
  scan_p2<<<dim3(256), blk, 0, stream>>>(fw_Alog, bw_Alog, hout, sumd);
  scan_p3<<<dim3(8, NC, 2), blk, 0, stream>>>(xz, u, xdbl, fw_Alog, bw_Alog, fw_Dp, bw_Dp, hout, g);

  // 6. out-proj: oproj[dir] = g @ out_w^T (fp32 out)
  gemm_bt<false><<<dim3(8, 8, 2), blk, 0, stream>>>(
      g, fw_out_w, bw_out_w, (void*)oproj, 1024, 1024, 2048, 2048, 2048, 1024,
      (long)1024 * 2048, (long)1024 * 1024, nullptr, nullptr, 0, 0, 0);

  // 7. residual + unflip + concat -> fused (bf16 1024x2048)
  fuse_k<<<8192, blk, 0, stream>>>(oproj, x, fused);

  // 8. final proj: fin = fused @ proj_w^T (fp32 out)
  gemm_bt<false><<<dim3(8, 8, 1), blk, 0, stream>>>(
      fused, proj_w, proj_w, (void*)fin, 1024, 1024, 2048, 2048, 2048, 1024,
      0L, 0L, nullptr, nullptr, 0, 0, 0);

  // 9. +proj_b, LayerNorm -> d_out (fp32)
  ln_k<<<1024, blk, 0, stream>>>(fin, proj_b, ln_w, ln_b, (float*)d_out);
}

// Round 4
// 454.953 us; speedup vs baseline: 2.9099x; 1.2557x over previous
//
#include <hip/hip_runtime.h>

typedef __bf16 bf16;
typedef __bf16 bf16x8 __attribute__((ext_vector_type(8)));
typedef float  f32x4  __attribute__((ext_vector_type(4)));

#define L_SEQ 1024
#define DM    1024
#define DI    2048
#define DTR   64
#define DSTATE 16
#define XD    96   // DT_RANK + 2*D_STATE
#define NC    32   // scan chunks
#define CS    32   // steps per chunk

__device__ __forceinline__ float bf2f(bf16 v){ return (float)v; }
__device__ __forceinline__ bf16  f2bf(float v){ return (bf16)v; }

// converted-weights element offsets inside wb
#define OFF_X      0L
#define OFF_INW    1048576L            // [2] x 4194304
#define OFF_XPROJ  9437184L            // [2] x 196608
#define OFF_DTW    9830400L            // [2] x 131072
#define OFF_OUTW   10092544L           // [2] x 2097152
#define OFF_PROJW  14286848L           // 2097152
#define CVT_TOTAL  16384000L

// ---------------------------------------------------------------------------
// fp32 -> bf16 conversion of x + all GEMM weights into wb (16.384M elems)
// ---------------------------------------------------------------------------
__global__ __launch_bounds__(256) void cvt_k(
    const float* __restrict__ x,
    const float* __restrict__ inw0, const float* __restrict__ inw1,
    const float* __restrict__ xp0,  const float* __restrict__ xp1,
    const float* __restrict__ dt0,  const float* __restrict__ dt1,
    const float* __restrict__ ow0,  const float* __restrict__ ow1,
    const float* __restrict__ pw,   bf16* __restrict__ wb)
{
  long i = ((long)blockIdx.x * 256 + threadIdx.x) * 8;
  if (i >= CVT_TOTAL) return;
  const float* src; long off;
  if      (i < OFF_INW)                 { src = x;    off = i - OFF_X; }
  else if (i < OFF_INW + 4194304L)      { src = inw0; off = i - OFF_INW; }
  else if (i < OFF_XPROJ)               { src = inw1; off = i - (OFF_INW + 4194304L); }
  else if (i < OFF_XPROJ + 196608L)     { src = xp0;  off = i - OFF_XPROJ; }
  else if (i < OFF_DTW)                 { src = xp1;  off = i - (OFF_XPROJ + 196608L); }
  else if (i < OFF_DTW + 131072L)       { src = dt0;  off = i - OFF_DTW; }
  else if (i < OFF_OUTW)                { src = dt1;  off = i - (OFF_DTW + 131072L); }
  else if (i < OFF_OUTW + 2097152L)     { src = ow0;  off = i - OFF_OUTW; }
  else if (i < OFF_PROJW)               { src = ow1;  off = i - (OFF_OUTW + 2097152L); }
  else                                  { src = pw;   off = i - OFF_PROJW; }
  f32x4 v0 = *(const f32x4*)(src + off);
  f32x4 v1 = *(const f32x4*)(src + off + 4);
  bf16x8 t;
  #pragma unroll
  for (int q = 0; q < 4; q++) { t[q] = (bf16)v0[q]; t[4+q] = (bf16)v1[q]; }
  *(bf16x8*)(wb + i) = t;
}

// ---------------------------------------------------------------------------
// All-bf16 MFMA GEMM, B^T layout: C[m][n] = sum_k A[m][k] * B[n][k]
// 128x128 tile, BK=64, 256 threads (4 waves, 2x2 of 64x64), 16x16x32 MFMA
// ---------------------------------------------------------------------------
__global__ __launch_bounds__(256) void gemm_bt(
    const bf16* __restrict__ A, const bf16* __restrict__ B0, const bf16* __restrict__ B1,
    void* __restrict__ Cv,
    int M, int N, int K, int lda, int ldb, int ldc,
    long aOffZ, long cOffZ,
    const float* __restrict__ bias0, const float* __restrict__ bias1,
    int flipA1, int writeBf16, int act)
{
  const int tid  = threadIdx.x;
  const int z    = blockIdx.z;
  const bf16*  Bp   = z ? B1 : B0;
  const float* bias = z ? bias1 : bias0;
  const int flip = z ? flipA1 : 0;
  const int bm = blockIdx.x * 128;
  const int bn = blockIdx.y * 128;

  __shared__ bf16 As[128][72];   // +8 pad: frag ds_read_b128 -> 2-way (free)
  __shared__ bf16 Bs[128][72];

  f32x4 acc[4][4];
  f32x4 z4; z4[0]=0.f; z4[1]=0.f; z4[2]=0.f; z4[3]=0.f;
  #pragma unroll
  for (int i=0;i<4;i++)
    #pragma unroll
    for (int j=0;j<4;j++) acc[i][j] = z4;

  const int wave = tid >> 6;
  const int lane = tid & 63;
  const int wm = (wave >> 1) * 64;
  const int wn = (wave & 1) * 64;
  const int fr = lane & 15;
  const int kq = (lane >> 4) * 8;

  const int srow = tid >> 1;
  const int scol = (tid & 1) * 32;

  int ar  = bm + srow;
  int agr = flip ? (M - 1 - ar) : ar;
  const bf16* aBase = A + (long)z * aOffZ + (long)agr * lda + scol;
  int br = bn + srow;
  const bf16* bBase = Bp + (long)br * ldb + scol;
  const bool bOk = (br < N);

  bf16x8 bz;
  #pragma unroll
  for (int q=0;q<8;q++) bz[q] = (bf16)0.f;

  for (int k0 = 0; k0 < K; k0 += 64) {
    bf16x8 a0 = *(const bf16x8*)(aBase + k0);
    bf16x8 a1 = *(const bf16x8*)(aBase + k0 + 8);
    bf16x8 a2 = *(const bf16x8*)(aBase + k0 + 16);
    bf16x8 a3 = *(const bf16x8*)(aBase + k0 + 24);
    bf16x8 b0 = bz, b1 = bz, b2 = bz, b3 = bz;
    if (bOk) {
      b0 = *(const bf16x8*)(bBase + k0);
      b1 = *(const bf16x8*)(bBase + k0 + 8);
      b2 = *(const bf16x8*)(bBase + k0 + 16);
      b3 = *(const bf16x8*)(bBase + k0 + 24);
    }
    *(bf16x8*)&As[srow][scol]      = a0;
    *(bf16x8*)&As[srow][scol + 8]  = a1;
    *(bf16x8*)&As[srow][scol + 16] = a2;
    *(bf16x8*)&As[srow][scol + 24] = a3;
    *(bf16x8*)&Bs[srow][scol]      = b0;
    *(bf16x8*)&Bs[srow][scol + 8]  = b1;
    *(bf16x8*)&Bs[srow][scol + 16] = b2;
    *(bf16x8*)&Bs[srow][scol + 24] = b3;
    __syncthreads();

    #pragma unroll
    for (int ks = 0; ks < 64; ks += 32) {
      bf16x8 af[4], bfr[4];
      #pragma unroll
      for (int i=0;i<4;i++) af[i]  = *(const bf16x8*)&As[wm + i*16 + fr][ks + kq];
      #pragma unroll
      for (int j=0;j<4;j++) bfr[j] = *(const bf16x8*)&Bs[wn + j*16 + fr][ks + kq];
      #pragma unroll
      for (int i=0;i<4;i++)
        #pragma unroll
        for (int j=0;j<4;j++)
          acc[i][j] = __builtin_amdgcn_mfma_f32_16x16x32_bf16(af[i], bfr[j], acc[i][j], 0, 0, 0);
    }
    __syncthreads();
  }

  const int rr = (lane >> 4) * 4;
  const int cc = lane & 15;
  #pragma unroll
  for (int i=0;i<4;i++) {
    #pragma unroll
    for (int j=0;j<4;j++) {
      int gn = bn + wn + j*16 + cc;
      if (gn >= N) continue;
      float bv = bias ? bias[gn] : 0.f;
      #pragma unroll
      for (int r=0;r<4;r++) {
        int gm = bm + wm + i*16 + rr + r;
        float v = acc[i][j][r] + bv;
        if (act == 1) v = (v > 20.f) ? v : log1pf(__expf(v));  // softplus
        long idx = (long)z * cOffZ + (long)gm * ldc + gn;
        if (writeBf16) ((bf16*)Cv)[idx] = f2bf(v);
        else           ((float*)Cv)[idx] = v;
      }
    }
  }
}

// ---------------------------------------------------------------------------
// depthwise causal conv(4) + bias + silu : u[dir][l][d]
// ---------------------------------------------------------------------------
__global__ __launch_bounds__(256) void conv_silu_k(
    const bf16* __restrict__ xz, const float* __restrict__ cw0, const float* __restrict__ cw1,
    const float* __restrict__ cb0, const float* __restrict__ cb1, bf16* __restrict__ u)
{
  int gid = blockIdx.x * 256 + threadIdx.x;       // over 2 * L * DI = 2^22
  int dir = gid >> 21;
  int rem = gid & ((1 << 21) - 1);
  int l = rem >> 11;
  int d = rem & (DI - 1);
  const float* w   = dir ? cw1 : cw0;
  const float* b   = dir ? cb1 : cb0;
  const bf16* xzd = xz + (long)dir * L_SEQ * (2 * DI);
  float acc = b[d];
  #pragma unroll
  for (int j = 0; j < 4; j++) {
    int ll = l - 3 + j;
    if (ll >= 0) acc += w[d * 4 + j] * bf2f(xzd[(long)ll * (2 * DI) + d]);
  }
  float s = acc / (1.f + __expf(-acc));
  u[(long)dir * L_SEQ * DI + (long)l * DI + d] = f2bf(s);
}

// ---------------------------------------------------------------------------
// Chunk-parallel selective scan (p1 local scan, p2 combine, p3 rescan+gate)
// ---------------------------------------------------------------------------
__global__ __launch_bounds__(256) void scan_p1(
    const bf16* __restrict__ xz, const bf16* __restrict__ u, const bf16* __restrict__ xdbl,
    const float* __restrict__ Alog0, const float* __restrict__ Alog1,
    bf16* __restrict__ hout, float* __restrict__ sumd)
{
  const int tid = threadIdx.x;
  const int c   = blockIdx.y;
  const int dir = blockIdx.z;
  const int d   = blockIdx.x * 256 + tid;
  const float* Alog = dir ? Alog1 : Alog0;
  const bf16* dl = xz + (long)dir * L_SEQ * (2 * DI);       // delta in xi cols
  const bf16* ud = u  + (long)dir * L_SEQ * DI;
  const bf16* xd = xdbl + (long)dir * L_SEQ * XD;
  const int l0 = c * CS;

  __shared__ float lb[CS][16];
  {
    int i = tid * 2;
    int ll = i >> 4, n = i & 15;
    const bf16* p = xd + (long)(l0 + ll) * XD + DTR + n;
    lb[ll][n]     = bf2f(p[0]);
    lb[ll][n + 1] = bf2f(p[1]);
  }
  __syncthreads();

  float An[16], h[16];
  #pragma unroll
  for (int n = 0; n < 16; n++) { An[n] = -__expf(Alog[d * 16 + n]); h[n] = 0.f; }
  float sd = 0.f;

  #pragma unroll 4
  for (int ll = 0; ll < CS; ll++) {
    int l = l0 + ll;
    float dlt = bf2f(dl[(long)l * (2 * DI) + d]);
    float uu  = bf2f(ud[(long)l * DI + d]);
    sd += dlt;
    float du = dlt * uu;
    #pragma unroll
    for (int n = 0; n < 16; n++) {
      float a = __expf(dlt * An[n]);
      h[n] = h[n] * a + du * lb[ll][n];
    }
  }

  bf16* hp = hout + (((long)dir * NC + c) * DI + d) * 16;
  bf16x8 o0, o1;
  #pragma unroll
  for (int n = 0; n < 8; n++) { o0[n] = f2bf(h[n]); o1[n] = f2bf(h[8 + n]); }
  *(bf16x8*)hp = o0;
  *(bf16x8*)(hp + 8) = o1;
  sumd[((long)dir * NC + c) * DI + d] = sd;
}

__global__ __launch_bounds__(256) void scan_p2(
    const float* __restrict__ Alog0, const float* __restrict__ Alog1,
    bf16* hout, const float* __restrict__ sumd)
{
  int g = blockIdx.x * 256 + threadIdx.x;   // 2*2048*16 = 65536
  int dir = g >> 15;
  int rem = g & 32767;
  int d = rem >> 4;
  int n = rem & 15;
  const float* Alog = dir ? Alog1 : Alog0;
  float An = -__expf(Alog[d * 16 + n]);
  float hs = 0.f;
  for (int c = 0; c < NC; c++) {
    long base = ((long)dir * NC + c) * DI + d;
    float tmp = bf2f(hout[base * 16 + n]);
    float P = __expf(An * sumd[base]);
    hout[base * 16 + n] = f2bf(hs);   // h_start for chunk c
    hs = P * hs + tmp;
  }
}

__global__ __launch_bounds__(256) void scan_p3(
    const bf16* xz, const bf16* u, const bf16* __restrict__ xdbl,
    const float* __restrict__ Alog0, const float* __restrict__ Alog1,
    const float* __restrict__ Dp0, const float* __restrict__ Dp1,
    const bf16* __restrict__ hout, bf16* g)
{
  const int tid = threadIdx.x;
  const int c   = blockIdx.y;
  const int dir = blockIdx.z;
  const int d   = blockIdx.x * 256 + tid;
  const float* Alog = dir ? Alog1 : Alog0;
  const float* Dp   = dir ? Dp1 : Dp0;
  const bf16* row0 = xz + (long)dir * L_SEQ * (2 * DI);   // delta @ +d, z @ +DI+d
  const bf16* ud   = u  + (long)dir * L_SEQ * DI;
  const bf16* xd   = xdbl + (long)dir * L_SEQ * XD;
  bf16* gd = g + (long)dir * L_SEQ * DI;
  const int l0 = c * CS;

  __shared__ float lb[CS][16];
  __shared__ float lc[CS][16];
  {
    int i = tid * 4;
    int ll = i >> 5, j = i & 31;
    const bf16* p = xd + (long)(l0 + ll) * XD + DTR + j;
    #pragma unroll
    for (int q = 0; q < 4; q++) {
      int jj = j + q;
      float v = bf2f(p[q]);
      if (jj < 16) lb[ll][jj] = v; else lc[ll][jj - 16] = v;
    }
  }
  __syncthreads();

  float An[16], h[16];
  const bf16* hp = hout + (((long)dir * NC + c) * DI + d) * 16;
  #pragma unroll
  for (int n = 0; n < 16; n++) {
    An[n] = -__expf(Alog[d * 16 + n]);
    h[n] = bf2f(hp[n]);
  }
  const float Dpv = Dp[d];

  #pragma unroll 4
  for (int ll = 0; ll < CS; ll++) {
    int l = l0 + ll;
    float dlt = bf2f(row0[(long)l * (2 * DI) + d]);
    float zv  = bf2f(row0[(long)l * (2 * DI) + DI + d]);
    float uu  = bf2f(ud[(long)l * DI + d]);
    float du = dlt * uu;
    float y = 0.f;
    #pragma unroll
    for (int n = 0; n < 16; n++) {
      float a = __expf(dlt * An[n]);
      h[n] = h[n] * a + du * lb[ll][n];
      y += h[n] * lc[ll][n];
    }
    y += uu * Dpv;
    float sz = zv / (1.f + __expf(-zv));
    gd[(long)l * DI + d] = f2bf(y * sz);
  }
}

// ---------------------------------------------------------------------------
// fused = [oproj_fw + x , flip(oproj_bw) + x]  (bf16, 1024 x 2048)
// ---------------------------------------------------------------------------
__global__ __launch_bounds__(256) void fuse_k(
    const float* __restrict__ oproj, const float* __restrict__ x, bf16* __restrict__ fused)
{
  int gid = blockIdx.x * 256 + threadIdx.x;  // over L * 2*DM = 2^21
  int l = gid >> 11;
  int c = gid & (2 * DM - 1);
  float v;
  if (c < DM) {
    v = oproj[(long)l * DM + c] + x[(long)l * DM + c];
  } else {
    int cc = c - DM;
    v = oproj[(long)L_SEQ * DM + (long)(L_SEQ - 1 - l) * DM + cc] + x[(long)l * DM + cc];
  }
  fused[gid] = f2bf(v);
}

// ---------------------------------------------------------------------------
// +proj_b then LayerNorm over last dim (1024), write fp32 out
// ---------------------------------------------------------------------------
__global__ __launch_bounds__(256) void ln_k(
    const float* __restrict__ fin, const float* __restrict__ pb,
    const float* __restrict__ lnw, const float* __restrict__ lnb, float* __restrict__ out)
{
  int row = blockIdx.x;
  int tid = threadIdx.x;
  float v[4]; float s1 = 0.f, s2 = 0.f;
  #pragma unroll
  for (int j = 0; j < 4; j++) {
    int c = tid + j * 256;
    v[j] = fin[(long)row * DM + c] + pb[c];
    s1 += v[j]; s2 += v[j] * v[j];
  }
  #pragma unroll
  for (int off = 32; off; off >>= 1) { s1 += __shfl_down(s1, off); s2 += __shfl_down(s2, off); }
  __shared__ float red[8];
  int wave = tid >> 6, lane = tid & 63;
  if (lane == 0) { red[wave] = s1; red[4 + wave] = s2; }
  __syncthreads();
  float t1 = red[0] + red[1] + red[2] + red[3];
  float t2 = red[4] + red[5] + red[6] + red[7];
  float mu = t1 / DM;
  float var = t2 / DM - mu * mu;
  float inv = rsqrtf(var + 1e-5f);
  #pragma unroll
  for (int j = 0; j < 4; j++) {
    int c = tid + j * 256;
    out[(long)row * DM + c] = (v[j] - mu) * inv * lnw[c] + lnb[c];
  }
}

// ---------------------------------------------------------------------------
extern "C" void kernel_launch(void* const* d_in, const int* in_sizes, int n_in,
                              void* d_out, int out_size, void* d_ws, size_t ws_size,
                              hipStream_t stream)
{
  const float* x         = (const float*)d_in[0];
  const float* fw_in_w   = (const float*)d_in[1];
  const float* fw_conv_w = (const float*)d_in[2];
  const float* fw_conv_b = (const float*)d_in[3];
  const float* fw_xproj_w= (const float*)d_in[4];
  const float* fw_dt_w   = (const float*)d_in[5];
  const float* fw_dt_b   = (const float*)d_in[6];
  const float* fw_Alog   = (const float*)d_in[7];
  const float* fw_Dp     = (const float*)d_in[8];
  const float* fw_out_w  = (const float*)d_in[9];
  const float* bw_in_w   = (const float*)d_in[10];
  const float* bw_conv_w = (const float*)d_in[11];
  const float* bw_conv_b = (const float*)d_in[12];
  const float* bw_xproj_w= (const float*)d_in[13];
  const float* bw_dt_w   = (const float*)d_in[14];
  const float* bw_dt_b   = (const float*)d_in[15];
  const float* bw_Alog   = (const float*)d_in[16];
  const float* bw_Dp     = (const float*)d_in[17];
  const float* bw_out_w  = (const float*)d_in[18];
  const float* proj_w    = (const float*)d_in[19];
  const float* proj_b    = (const float*)d_in[20];
  const float* ln_w      = (const float*)d_in[21];
  const float* ln_b      = (const float*)d_in[22];

  // workspace layout (peak ~62.3 MB):
  //   xz bf16 [2][1024][4096]  @ 0..16MB     (delta overwrites xi cols)
  //   u/g bf16 [2][1024][2048] @ 16..24MB    (g in-place over u)
  //   xdbl bf16 [2][1024][96]  @ 24..24.4MB
  //   sumd f32 [2][32][2048]   @ 25..25.5MB
  //   hout bf16 [2][32][2048][16] @ 26..30MB
  //   wb bf16 (converted x + weights, 16.384M elems) @ 30..61.3MB
  //   phase 2: oproj f32 @0..8, fused bf16 @8..12, fin f32 @12..16 (xz dead)
  char* ws = (char*)d_ws;
  const size_t MB = 1024 * 1024;
  bf16*  xz    = (bf16*)(ws + 0);
  bf16*  u     = (bf16*)(ws + 16 * MB);
  bf16*  xdbl  = (bf16*)(ws + 24 * MB);
  float* sumd  = (float*)(ws + 25 * MB);
  bf16*  hout  = (bf16*)(ws + 26 * MB);
  bf16*  wb    = (bf16*)(ws + 30 * MB);
  bf16*  g     = u;
  bf16*  delta = xz;                      // xi columns, stride 4096
  float* oproj = (float*)(ws + 0);
  bf16*  fused = (bf16*)(ws + 8 * MB);
  float* fin   = (float*)(ws + 12 * MB);

  bf16* xb     = wb + OFF_X;
  bf16* inw    = wb + OFF_INW;     // [2][4096][1024]
  bf16* xprojw = wb + OFF_XPROJ;   // [2][96][2048]
  bf16* dtw    = wb + OFF_DTW;     // [2][2048][64]
  bf16* outw   = wb + OFF_OUTW;    // [2][1024][2048]
  bf16* projw  = wb + OFF_PROJW;   // [1024][2048]

  dim3 blk(256);

  // 0. convert x + weights to bf16
  cvt_k<<<(CVT_TOTAL / 8 + 255) / 256, blk, 0, stream>>>(
      x, fw_in_w, bw_in_w, fw_xproj_w, bw_xproj_w, fw_dt_w, bw_dt_w,
      fw_out_w, bw_out_w, proj_w, wb);

  // 1. in-proj: xz[dir] = (flip?)xb @ in_w^T   (M=1024, N=4096, K=1024)
  gemm_bt<<<dim3(8, 32, 2), blk, 0, stream>>>(
      xb, inw, inw + 4194304L, (void*)xz, 1024, 4096, 1024, 1024, 1024, 4096,
      0L, (long)1024 * 4096, nullptr, nullptr, 1, 1, 0);

  // 2. depthwise conv + silu -> u
  conv_silu_k<<<16384, blk, 0, stream>>>(xz, fw_conv_w, bw_conv_w, fw_conv_b, bw_conv_b, u);

  // 3. x_dbl = u @ xproj_w^T   (N=96)
  gemm_bt<<<dim3(8, 1, 2), blk, 0, stream>>>(
      u, xprojw, xprojw + 196608L, (void*)xdbl, 1024, 96, 2048, 2048, 2048, 96,
      (long)1024 * 2048, (long)1024 * 96, nullptr, nullptr, 0, 1, 0);

  // 4. delta = softplus(dt @ dt_w^T + dt_b) -> xi cols of xz (ldc=4096)
  gemm_bt<<<dim3(8, 16, 2), blk, 0, stream>>>(
      xdbl, dtw, dtw + 131072L, (void*)delta, 1024, 2048, 64, 96, 64, 4096,
      (long)1024 * 96, (long)1024 * 4096, fw_dt_b, bw_dt_b, 0, 1, 1);

  // 5. chunk-parallel selective scan -> g = (y + u*Dp)*silu(z)  (in-place over u)
  scan_p1<<<dim3(8, NC, 2), blk, 0, stream>>>(xz, u, xdbl, fw_Alog, bw_Alog, hout, sumd);
  scan_p2<<<dim3(256), blk, 0, stream>>>(fw_Alog, bw_Alog, hout, sumd);
  scan_p3<<<dim3(8, NC, 2), blk, 0, stream>>>(xz, u, xdbl, fw_Alog, bw_Alog, fw_Dp, bw_Dp, hout, g);

  // 6. out-proj: oproj[dir] = g @ out_w^T (fp32 out)
  gemm_bt<<<dim3(8, 8, 2), blk, 0, stream>>>(
      g, outw, outw + 2097152L, (void*)oproj, 1024, 1024, 2048, 2048, 2048, 1024,
      (long)1024 * 2048, (long)1024 * 1024, nullptr, nullptr, 0, 0, 0);

  // 7. residual + unflip + concat -> fused (bf16 1024x2048)
  fuse_k<<<8192, blk, 0, stream>>>(oproj, x, fused);

  // 8. final proj: fin = fused @ proj_w^T (fp32 out)
  gemm_bt<<<dim3(8, 8, 1), blk, 0, stream>>>(
      fused, projw, projw, (void*)fin, 1024, 1024, 2048, 2048, 2048, 1024,
      0L, 0L, nullptr, nullptr, 0, 0, 0);

  // 9. +proj_b, LayerNorm -> d_out (fp32)
  ln_k<<<1024, blk, 0, stream>>>(fin, proj_b, ln_w, ln_b, (float*)d_out);
}